// Round 4
// baseline (804.690 us; speedup 1.0000x reference)
//
#include <hip/hip_runtime.h>
#include <hip/hip_bf16.h>

// MoE block: N=8192 tokens, D=1024, H=1024, E=16 experts, top-k=2.
// Inputs fp32 (confirmed: bf16 reinterpretation caused NaN in rounds 1-2).
// Output fp32 (reference returns float32; harness rule = reference output
// dtype; round-3 bf16 writes produced exactly the observed garbage pattern).
//
// out[n] = w1*(x[n]@W_e1 + b_e1) + w2*(x[n]@W_e2 + b_e2), w = top-2 softmax.
//
//   1) router_kernel: fp64 logits, softmax, top-2; bucket tokens into TWO
//      per-expert lists (slot0 = top-1 entries, slot1 = top-2 entries).
//   2) expert_gemm<ADD=false>: grouped GEMM over slot-0 lists, writes
//      w*(x@W+b) (fp32) directly to d_out — covers every token row once.
//   3) expert_gemm<ADD=true>: slot-1 lists, out += w*(x@W+b).
//      Stream-ordered after pass A; one entry per token per pass -> race-free.

#define N_TOK 8192
#define D_DIM 1024
#define H_DIM 1024
#define E_NUM 16
#define CAP   1024   // per-expert per-slot capacity (expected ~512, sigma ~28)

__global__ __launch_bounds__(256) void router_kernel(
    const float* __restrict__ x,
    const float* __restrict__ rw,
    const float* __restrict__ rb,
    int* __restrict__ counts0, int* __restrict__ counts1,
    int2* __restrict__ entries0, int2* __restrict__ entries1)
{
    const int wave = threadIdx.x >> 6;
    const int lane = threadIdx.x & 63;
    const int n = blockIdx.x * 4 + wave;

    double acc[E_NUM];
#pragma unroll
    for (int e = 0; e < E_NUM; ++e) acc[e] = 0.0;

    const float* xrow = x + (size_t)n * D_DIM;
    for (int j = 0; j < D_DIM / 64; ++j) {
        const int d = lane + j * 64;
        const double xv = (double)xrow[d];
        const float* wrow = rw + d * E_NUM;
#pragma unroll
        for (int e = 0; e < E_NUM; ++e)
            acc[e] += xv * (double)wrow[e];
    }

#pragma unroll
    for (int e = 0; e < E_NUM; ++e) {
        double v = acc[e];
#pragma unroll
        for (int off = 32; off > 0; off >>= 1)
            v += __shfl_xor(v, off);
        acc[e] = v + (double)rb[e];
    }

    if (lane == 0) {
        double m = acc[0];
#pragma unroll
        for (int e = 1; e < E_NUM; ++e) m = fmax(m, acc[e]);
        double p[E_NUM];
        double s = 0.0;
#pragma unroll
        for (int e = 0; e < E_NUM; ++e) { p[e] = exp(acc[e] - m); s += p[e]; }

        // top-1 (earliest index on ties, matching lax.top_k), then top-2
        int e1 = 0;
#pragma unroll
        for (int e = 1; e < E_NUM; ++e) if (acc[e] > acc[e1]) e1 = e;
        int e2 = (e1 == 0) ? 1 : 0;
        for (int e = 0; e < E_NUM; ++e)
            if (e != e1 && acc[e] > acc[e2]) e2 = e;

        const float w1 = (float)(p[e1] / s);
        const float w2 = (float)(p[e2] / s);

        int pos1 = atomicAdd(&counts0[e1], 1);
        if (pos1 < CAP) entries0[e1 * CAP + pos1] = make_int2(n, __float_as_int(w1));
        int pos2 = atomicAdd(&counts1[e2], 1);
        if (pos2 < CAP) entries1[e2 * CAP + pos2] = make_int2(n, __float_as_int(w2));
    }
}

#define BT 64
#define BH 64
#define BK 32

template <bool ADD>
__global__ __launch_bounds__(256) void expert_gemm_kernel(
    const float* __restrict__ x,
    const float* __restrict__ ew,
    const float* __restrict__ eb,
    const int* __restrict__ counts,
    const int2* __restrict__ entries,
    float* __restrict__ out)
{
    const int e = blockIdx.z;
    int count = counts[e];
    if (count > CAP) count = CAP;
    const int i0 = blockIdx.y * BT;
    if (i0 >= count) return;
    const int h0 = blockIdx.x * BH;

    __shared__ float Xs[BT][BK];
    __shared__ float Ws[BK][BH];
    __shared__ int   s_tok[BT];
    __shared__ float s_w[BT];

    const int tid = threadIdx.x;
    if (tid < BT) {
        const int i = i0 + tid;
        if (i < count) {
            int2 en = entries[e * CAP + i];
            s_tok[tid] = en.x;
            s_w[tid] = __int_as_float(en.y);
        } else {
            s_tok[tid] = 0;   // safe dummy token (result discarded)
            s_w[tid] = 0.0f;
        }
    }
    __syncthreads();

    const int tx = tid & 15;   // col group: h0 + tx*4 .. +3
    const int ty = tid >> 4;   // row group: ty*4 .. +3

    float acc[4][4] = {};

    const int xr = tid >> 2;          // Xs row (0..63)
    const int xc = (tid & 3) * 4;     // Xs col start; two float4 loads (xc, xc+16)
    const int wr = tid >> 3;          // Ws row (0..31)
    const int wc = (tid & 7) * 4;     // Ws col start; two float4 loads (wc, wc+32)

    const int xtok = s_tok[xr];
    const float* xbase = x + (size_t)xtok * D_DIM;
    const float* wbase = ew + (size_t)e * D_DIM * H_DIM;

    for (int d0 = 0; d0 < D_DIM; d0 += BK) {
        *(float4*)&Xs[xr][xc]      = *(const float4*)(xbase + d0 + xc);
        *(float4*)&Xs[xr][xc + 16] = *(const float4*)(xbase + d0 + xc + 16);
        const float* wrow = wbase + (size_t)(d0 + wr) * H_DIM + h0;
        *(float4*)&Ws[wr][wc]      = *(const float4*)(wrow + wc);
        *(float4*)&Ws[wr][wc + 32] = *(const float4*)(wrow + wc + 32);
        __syncthreads();

#pragma unroll
        for (int kk = 0; kk < BK; ++kk) {
            const float a0 = Xs[ty * 4 + 0][kk];
            const float a1 = Xs[ty * 4 + 1][kk];
            const float a2 = Xs[ty * 4 + 2][kk];
            const float a3 = Xs[ty * 4 + 3][kk];
            const float4 b = *(const float4*)&Ws[kk][tx * 4];
            acc[0][0] += a0 * b.x; acc[0][1] += a0 * b.y; acc[0][2] += a0 * b.z; acc[0][3] += a0 * b.w;
            acc[1][0] += a1 * b.x; acc[1][1] += a1 * b.y; acc[1][2] += a1 * b.z; acc[1][3] += a1 * b.w;
            acc[2][0] += a2 * b.x; acc[2][1] += a2 * b.y; acc[2][2] += a2 * b.z; acc[2][3] += a2 * b.w;
            acc[3][0] += a3 * b.x; acc[3][1] += a3 * b.y; acc[3][2] += a3 * b.z; acc[3][3] += a3 * b.w;
        }
        __syncthreads();
    }

    const int hb = h0 + tx * 4;
    const float4 bias = *(const float4*)(eb + e * H_DIM + hb);

#pragma unroll
    for (int i = 0; i < 4; ++i) {
        const int r = ty * 4 + i;
        if (i0 + r < count) {
            const int tok = s_tok[r];
            const float w = s_w[r];
            float4 o;
            o.x = w * (acc[i][0] + bias.x);
            o.y = w * (acc[i][1] + bias.y);
            o.z = w * (acc[i][2] + bias.z);
            o.w = w * (acc[i][3] + bias.w);
            float* op = out + (size_t)tok * H_DIM + hb;
            if (ADD) {
                float4 cur = *(const float4*)op;
                o.x += cur.x; o.y += cur.y; o.z += cur.z; o.w += cur.w;
            }
            *(float4*)op = o;
        }
    }
}

extern "C" void kernel_launch(void* const* d_in, const int* in_sizes, int n_in,
                              void* d_out, int out_size, void* d_ws, size_t ws_size,
                              hipStream_t stream)
{
    const float* x  = (const float*)d_in[0];
    const float* rw = (const float*)d_in[1];
    const float* rb = (const float*)d_in[2];
    const float* ew = (const float*)d_in[3];
    const float* eb = (const float*)d_in[4];
    // d_in[5] = k (fixed 2)

    char* ws = (char*)d_ws;
    int*  counts0  = (int*)ws;            // 64 B
    int*  counts1  = (int*)(ws + 64);     // 64 B
    int2* entries0 = (int2*)(ws + 1024);                       // 128 KB
    int2* entries1 = (int2*)(ws + 1024 + E_NUM * CAP * 8);     // 128 KB

    hipMemsetAsync(ws, 0, 128, stream);

    router_kernel<<<N_TOK / 4, 256, 0, stream>>>(x, rw, rb, counts0, counts1,
                                                 entries0, entries1);

    dim3 grid(H_DIM / BH, CAP / BT, E_NUM);
    expert_gemm_kernel<false><<<grid, 256, 0, stream>>>(
        x, ew, eb, counts0, entries0, (float*)d_out);
    expert_gemm_kernel<true><<<grid, 256, 0, stream>>>(
        x, ew, eb, counts1, entries1, (float*)d_out);
}

// Round 5
// 419.778 us; speedup vs baseline: 1.9169x; 1.9169x over previous
//
#include <hip/hip_runtime.h>
#include <hip/hip_bf16.h>

// MoE block: N=8192, D=1024, H=1024, E=16, top-k=2. Inputs fp32, output fp32.
// out[n] = w1*(x@W_e1 + b_e1) + w2*(x@W_e2 + b_e2), w = top-2 of softmax.
//
// Round-5: expert GEMM moved to bf16 MFMA (16x16x32), fp32->bf16 RNE cast
// during LDS staging. 128x128 tile, BK=32, 4 waves of 64x64 (4x4 frags).
// LDS rows padded to 40 ushorts (80 B): 16B-aligned for ds_read_b128 and
// conflict-free start-bank spread. W staged transposed (Ws[n][k]) so the
// B-operand fragment (lane n=lane&15, k=quad*8+j) is one contiguous b128.
//   pass A (ADD=0): slot-0 lists -> out = w*(x@W+b)   (covers every token)
//   pass B (ADD=1): slot-1 lists -> out += w*(x@W+b)  (fp32 RMW, race-free)

#define N_TOK 8192
#define D_DIM 1024
#define H_DIM 1024
#define E_NUM 16
#define CAP   1024
#define KPAD  40    // LDS row stride in ushorts (80 B)

typedef __attribute__((ext_vector_type(4))) float f32x4;
typedef __attribute__((ext_vector_type(8))) short bf16x8;

__device__ __forceinline__ unsigned short f2bf(float f) {
    unsigned int u = __float_as_uint(f);
    unsigned int r = u + 0x7fffu + ((u >> 16) & 1u);   // RNE
    return (unsigned short)(r >> 16);
}
__device__ __forceinline__ unsigned int pk2bf(float lo, float hi) {
    return (unsigned int)f2bf(lo) | ((unsigned int)f2bf(hi) << 16);
}

__global__ __launch_bounds__(256) void router_kernel(
    const float* __restrict__ x,
    const float* __restrict__ rw,
    const float* __restrict__ rb,
    int* __restrict__ counts0, int* __restrict__ counts1,
    int2* __restrict__ entries0, int2* __restrict__ entries1)
{
    const int wave = threadIdx.x >> 6;
    const int lane = threadIdx.x & 63;
    const int n = blockIdx.x * 4 + wave;

    double acc[E_NUM];
#pragma unroll
    for (int e = 0; e < E_NUM; ++e) acc[e] = 0.0;

    const float* xrow = x + (size_t)n * D_DIM;
    for (int j = 0; j < D_DIM / 64; ++j) {
        const int d = lane + j * 64;
        const double xv = (double)xrow[d];
        const float* wrow = rw + d * E_NUM;
#pragma unroll
        for (int e = 0; e < E_NUM; ++e)
            acc[e] += xv * (double)wrow[e];
    }

#pragma unroll
    for (int e = 0; e < E_NUM; ++e) {
        double v = acc[e];
#pragma unroll
        for (int off = 32; off > 0; off >>= 1)
            v += __shfl_xor(v, off);
        acc[e] = v + (double)rb[e];
    }

    if (lane == 0) {
        double m = acc[0];
#pragma unroll
        for (int e = 1; e < E_NUM; ++e) m = fmax(m, acc[e]);
        double p[E_NUM];
        double s = 0.0;
#pragma unroll
        for (int e = 0; e < E_NUM; ++e) { p[e] = exp(acc[e] - m); s += p[e]; }

        int e1 = 0;
#pragma unroll
        for (int e = 1; e < E_NUM; ++e) if (acc[e] > acc[e1]) e1 = e;
        int e2 = (e1 == 0) ? 1 : 0;
        for (int e = 0; e < E_NUM; ++e)
            if (e != e1 && acc[e] > acc[e2]) e2 = e;

        const float w1 = (float)(p[e1] / s);
        const float w2 = (float)(p[e2] / s);

        int pos1 = atomicAdd(&counts0[e1], 1);
        if (pos1 < CAP) entries0[e1 * CAP + pos1] = make_int2(n, __float_as_int(w1));
        int pos2 = atomicAdd(&counts1[e2], 1);
        if (pos2 < CAP) entries1[e2 * CAP + pos2] = make_int2(n, __float_as_int(w2));
    }
}

template <bool ADD>
__global__ __launch_bounds__(256) void moe_mfma_kernel(
    const float* __restrict__ x,
    const float* __restrict__ ew,
    const float* __restrict__ eb,
    const int* __restrict__ counts,
    const int2* __restrict__ entries,
    float* __restrict__ out)
{
    const int e = blockIdx.z;
    int count = counts[e];
    if (count > CAP) count = CAP;
    const int i0 = blockIdx.y * 128;
    if (i0 >= count) return;
    const int h0 = blockIdx.x * 128;

    __shared__ unsigned short Xs[128][KPAD];   // [token_row][k]
    __shared__ unsigned short Ws[128][KPAD];   // [h_col][k]  (W transposed)
    __shared__ int   s_tok[128];
    __shared__ float s_w[128];

    const int tid = threadIdx.x;
    if (tid < 128) {
        const int i = i0 + tid;
        if (i < count) {
            int2 en = entries[e * CAP + i];
            s_tok[tid] = en.x;
            s_w[tid] = __int_as_float(en.y);
        } else {
            s_tok[tid] = 0;
            s_w[tid] = 0.0f;
        }
    }
    __syncthreads();

    const int wave = tid >> 6;
    const int lane = tid & 63;
    const int wr = (wave >> 1) * 64;   // wave's token-row offset
    const int wc = (wave & 1) * 64;    // wave's h-col offset
    const int l15 = lane & 15;
    const int quad = lane >> 4;

    f32x4 acc[4][4] = {};   // [token 16-block][h 16-block]

    // A staging map: thread -> (k-quad, row set)
    const int a_kq = (tid & 7) * 4;    // k offset (float4)
    const int a_r0 = tid >> 3;         // 0..31, rows a_r0 + 32*it
    // B staging map: thread -> one h column, 16 k values
    const int b_n  = tid & 127;
    const int b_dh = (tid >> 7) * 16;  // 0 or 16

    const float* wcol = ew + (size_t)e * D_DIM * H_DIM + h0 + b_n;

    for (int d0 = 0; d0 < D_DIM; d0 += 32) {
        // ---- stage A: 128x32 fp32 -> bf16, row-major
#pragma unroll
        for (int it = 0; it < 4; ++it) {
            const int r = a_r0 + it * 32;
            const float4 v = *(const float4*)(x + (size_t)s_tok[r] * D_DIM + d0 + a_kq);
            ushort4 p;
            p.x = f2bf(v.x); p.y = f2bf(v.y); p.z = f2bf(v.z); p.w = f2bf(v.w);
            *(ushort4*)&Xs[r][a_kq] = p;   // 8B-aligned (80*r + 2*a_kq)
        }
        // ---- stage B: 32x128 fp32 -> bf16 transposed into Ws[n][k]
        {
            float t[16];
#pragma unroll
            for (int i = 0; i < 16; ++i)
                t[i] = wcol[(size_t)(d0 + b_dh + i) * H_DIM];
            uint4 lo, hi;
            lo.x = pk2bf(t[0], t[1]);  lo.y = pk2bf(t[2], t[3]);
            lo.z = pk2bf(t[4], t[5]);  lo.w = pk2bf(t[6], t[7]);
            hi.x = pk2bf(t[8], t[9]);  hi.y = pk2bf(t[10], t[11]);
            hi.z = pk2bf(t[12], t[13]); hi.w = pk2bf(t[14], t[15]);
            *(uint4*)&Ws[b_n][b_dh]     = lo;   // 16B-aligned (80*n + 2*b_dh)
            *(uint4*)&Ws[b_n][b_dh + 8] = hi;
        }
        __syncthreads();

        // ---- fragments + MFMA
        bf16x8 af[4], bq[4];
#pragma unroll
        for (int i = 0; i < 4; ++i)
            af[i] = *(const bf16x8*)&Xs[wr + i * 16 + l15][quad * 8];
#pragma unroll
        for (int j = 0; j < 4; ++j)
            bq[j] = *(const bf16x8*)&Ws[wc + j * 16 + l15][quad * 8];
#pragma unroll
        for (int i = 0; i < 4; ++i)
#pragma unroll
            for (int j = 0; j < 4; ++j)
                acc[i][j] = __builtin_amdgcn_mfma_f32_16x16x32_bf16(
                    af[i], bq[j], acc[i][j], 0, 0, 0);

        __syncthreads();
    }

    // ---- epilogue: D row = quad*4 + reg (token), col = l15 (h)
    float bias_j[4];
    const float* ebp = eb + e * H_DIM + h0 + wc;
#pragma unroll
    for (int j = 0; j < 4; ++j) bias_j[j] = ebp[j * 16 + l15];

#pragma unroll
    for (int i = 0; i < 4; ++i) {
#pragma unroll
        for (int r = 0; r < 4; ++r) {
            const int row = wr + i * 16 + quad * 4 + r;
            if (i0 + row < count) {
                const int tok = s_tok[row];
                const float w = s_w[row];
                float* op = out + (size_t)tok * H_DIM + h0 + wc + l15;
#pragma unroll
                for (int j = 0; j < 4; ++j) {
                    float v = w * (acc[i][j][r] + bias_j[j]);
                    if (ADD) v += op[j * 16];
                    op[j * 16] = v;
                }
            }
        }
    }
}

extern "C" void kernel_launch(void* const* d_in, const int* in_sizes, int n_in,
                              void* d_out, int out_size, void* d_ws, size_t ws_size,
                              hipStream_t stream)
{
    const float* x  = (const float*)d_in[0];
    const float* rw = (const float*)d_in[1];
    const float* rb = (const float*)d_in[2];
    const float* ew = (const float*)d_in[3];
    const float* eb = (const float*)d_in[4];

    char* ws = (char*)d_ws;
    int*  counts0  = (int*)ws;
    int*  counts1  = (int*)(ws + 64);
    int2* entries0 = (int2*)(ws + 1024);
    int2* entries1 = (int2*)(ws + 1024 + E_NUM * CAP * 8);

    hipMemsetAsync(ws, 0, 128, stream);

    router_kernel<<<N_TOK / 4, 256, 0, stream>>>(x, rw, rb, counts0, counts1,
                                                 entries0, entries1);

    dim3 grid(H_DIM / 128, CAP / 128, E_NUM);
    moe_mfma_kernel<false><<<grid, 256, 0, stream>>>(
        x, ew, eb, counts0, entries0, (float*)d_out);
    moe_mfma_kernel<true><<<grid, 256, 0, stream>>>(
        x, ew, eb, counts1, entries1, (float*)d_out);
}